// Round 1
// baseline (13595.552 us; speedup 1.0000x reference)
//
#include <hip/hip_runtime.h>
#include <stdint.h>
#include <stddef.h>

// Problem constants
constexpr int V = 32000, E = 256, H = 512, B = 64, T = 512;

// Partitioning: 4 batch-groups x 16 batches; 64 row-chunks x 8 hidden units.
constexpr int NG = 4;            // batch groups
constexpr int BPG = 64;          // blocks per group
constexpr int BATG = 16;         // batches per group
constexpr int HPB = 8;           // hidden units per block
constexpr int ROWS = 32;         // gate rows per block (4 gates x HPB)
constexpr int KTOT = 768;        // H + E
constexpr int NTHR = 256;

// LDS strides (padded against bank conflicts)
constexpr int WSTR = 772;        // floats per W row
constexpr int ZSTR = 770;        // bf16 elements per z row
constexpr int PSTR = 529;        // floats per partial ks-row

constexpr int OFF_W    = 0;
constexpr int OFF_Z    = OFF_W + ROWS * WSTR * 4;        // 98816
constexpr int OFF_P    = OFF_Z + BATG * ZSTR * 2;        // 123456
constexpr int OFF_BIAS = OFF_P + 16 * PSTR * 4;          // 157312
constexpr int OFF_C    = OFF_BIAS + ROWS * 4;            // 157440
constexpr int OFF_EX   = OFF_C + HPB * BATG * 4;         // 157952
constexpr int OFF_LEN  = OFF_EX + 2 * 128 * 4;           // 158976
constexpr int OFF_TOK  = OFF_LEN + BATG * 4;             // 159040
constexpr int LDS_BYTES = OFF_TOK + BATG * 4;            // 159104 (<= 163840)

// Output layout (flat fp32): output | hT | cT | mask
constexpr size_t OUT_HT   = (size_t)B * T * H;           // 16777216
constexpr size_t OUT_CT   = OUT_HT + (size_t)B * H;      // 16809984
constexpr size_t OUT_MASK = OUT_CT + (size_t)B * H;      // 16842752

__device__ __forceinline__ float bflo(uint32_t u) {
  return __builtin_bit_cast(float, u << 16);
}
__device__ __forceinline__ float bfhi(uint32_t u) {
  return __builtin_bit_cast(float, u & 0xffff0000u);
}
__device__ __forceinline__ uint32_t f2bf(float f) {  // round-to-nearest-even
  uint32_t u = __builtin_bit_cast(uint32_t, f);
  return (u + 0x7fffu + ((u >> 16) & 1u)) >> 16;
}

// 64-block group barrier: monotonic counter, agent scope (cross-XCD safe).
__device__ __forceinline__ void group_barrier(int* c, int target) {
  __syncthreads();
  if (threadIdx.x == 0) {
    __threadfence();
    __hip_atomic_fetch_add(c, 1, __ATOMIC_RELEASE, __HIP_MEMORY_SCOPE_AGENT);
    while (__hip_atomic_load(c, __ATOMIC_ACQUIRE, __HIP_MEMORY_SCOPE_AGENT) < target) {
      __builtin_amdgcn_s_sleep(2);
    }
  }
  __syncthreads();
}

__global__ void __launch_bounds__(NTHR, 1)
lstm_persistent(const int* __restrict__ inputs, const int* __restrict__ lengths,
                const int* __restrict__ resets, const float* __restrict__ emb,
                const float* __restrict__ W_ih, const float* __restrict__ W_hh,
                const float* __restrict__ b_ih, const float* __restrict__ b_hh,
                float* __restrict__ out, int* __restrict__ ctr,
                float* __restrict__ hbuf) {
  extern __shared__ char lds[];
  float* Ws = (float*)(lds + OFF_W);
  unsigned short* Zs = (unsigned short*)(lds + OFF_Z);
  float* Ps = (float*)(lds + OFF_P);
  float* Bias = (float*)(lds + OFF_BIAS);
  float* Cs = (float*)(lds + OFF_C);
  float* Ex = (float*)(lds + OFF_EX);
  int* Lens = (int*)(lds + OFF_LEN);
  int* Tok = (int*)(lds + OFF_TOK);

  const int tid = threadIdx.x;
  const int blk = blockIdx.x;
  const int grp = blk & 3;         // batch group
  const int rq = blk >> 2;         // row chunk 0..63
  const int khid = rq * HPB;       // hidden-unit base
  const int b0 = grp * BATG;       // batch base
  int* mybar = ctr + grp * 64;     // 256B-separated counters

  // ---- init: W slice -> LDS (fp32). Row r: gate = r>>3, unit = khid + (r&7).
  for (int r = 0; r < ROWS; ++r) {
    const int grow = (r >> 3) * H + khid + (r & 7);
    const float* hh = W_hh + (size_t)grow * H;
    const float* ih = W_ih + (size_t)grow * E;
    for (int k = tid; k < H; k += NTHR) Ws[r * WSTR + k] = hh[k];
    for (int k = tid; k < E; k += NTHR) Ws[r * WSTR + H + k] = ih[k];
  }
  if (tid < ROWS) {
    const int grow = (tid >> 3) * H + khid + (tid & 7);
    Bias[tid] = b_ih[grow] + b_hh[grow];
  }
  if (tid < BATG) Lens[tid] = lengths[b0 + tid];
  if (tid < HPB * BATG) Cs[tid] = 0.f;
  if (tid < BATG * HPB) {          // zero h ping-pong buffer 0 (our slice)
    int bb = tid >> 3, j = tid & 7;
    hbuf[(size_t)(b0 + bb) * H + khid + j] = 0.f;
  }
  int bar = 1;
  group_barrier(mybar, 64 * bar); bar++;

  // FMA-phase tiling ids: tid = tileq*16 + ks; tileq = rowq*4 + bq
  const int ks = tid & 15;
  const int tileq = tid >> 4;
  const int rowq = tileq >> 2;
  const int bq = tileq & 3;
  // epilogue ids
  const int gsel = tid >> 7;       // 0: gates i,f  1: gates g,o
  const int p2 = tid & 127;
  const int jj = p2 >> 4;          // hidden j 0..7
  const int bbp = p2 & 15;         // batch 0..15

  float carry_h = 0.f, carry_c = 0.f;

  for (int t = 0; t < T; ++t) {
    const float* hsrc = hbuf + (size_t)(t & 1) * (B * H);
    float* hdst = hbuf + (size_t)((t + 1) & 1) * (B * H);

    if (tid < BATG) Tok[tid] = inputs[(b0 + tid) * T + t];
    __syncthreads();

    // ---- stage z = [h ; x] as bf16 into LDS
    #pragma unroll
    for (int ii = 0; ii < 16; ++ii) {      // h: 4096 float2
      int idx = tid + NTHR * ii;
      int bb = idx >> 8, k2 = idx & 255;
      float2 hv = *(const float2*)(hsrc + (size_t)(b0 + bb) * H + k2 * 2);
      uint32_t pack = f2bf(hv.x) | (f2bf(hv.y) << 16);
      *(uint32_t*)(Zs + bb * ZSTR + k2 * 2) = pack;
    }
    #pragma unroll
    for (int ii = 0; ii < 8; ++ii) {       // x = emb[token]: 2048 float2
      int idx = tid + NTHR * ii;
      int bb = idx >> 7, e2 = idx & 127;
      float2 xv = *(const float2*)(emb + (size_t)Tok[bb] * E + e2 * 2);
      uint32_t pack = f2bf(xv.x) | (f2bf(xv.y) << 16);
      *(uint32_t*)(Zs + bb * ZSTR + H + e2 * 2) = pack;
    }
    __syncthreads();

    // ---- FMA: 8 rows x 4 batches per thread, K split 16 ways
    float acc[8][4];
    #pragma unroll
    for (int j = 0; j < 8; ++j)
      #pragma unroll
      for (int jb = 0; jb < 4; ++jb) acc[j][jb] = 0.f;

    const float* wbase = Ws + (rowq * 8) * WSTR;
    const unsigned short* zbase = Zs + (bq * 4) * ZSTR;
    for (int i = 0; i < 24; ++i) {
      const int k = 2 * (ks + 16 * i);
      float zl[4], zh[4];
      #pragma unroll
      for (int jb = 0; jb < 4; ++jb) {
        uint32_t u = *(const uint32_t*)(zbase + jb * ZSTR + k);
        zl[jb] = bflo(u); zh[jb] = bfhi(u);
      }
      #pragma unroll
      for (int j = 0; j < 8; ++j) {
        float2 w = *(const float2*)(wbase + j * WSTR + k);
        #pragma unroll
        for (int jb = 0; jb < 4; ++jb)
          acc[j][jb] = fmaf(w.y, zh[jb], fmaf(w.x, zl[jb], acc[j][jb]));
      }
    }
    // write K-partials
    #pragma unroll
    for (int j = 0; j < 8; ++j)
      #pragma unroll
      for (int jb = 0; jb < 4; ++jb) {
        int o = (rowq * 8 + j) * 16 + (bq * 4 + jb);
        Ps[ks * PSTR + o] = acc[j][jb];
      }
    __syncthreads();

    // ---- reduce 16 partials + bias (rotated reads to dodge bank conflicts)
    const int r0 = gsel * 16 + jj;   // gate 2*gsel, row j
    const int r1 = r0 + 8;           // gate 2*gsel+1
    const int o0 = r0 * 16 + bbp, o1 = r1 * 16 + bbp;
    float s0 = Bias[r0], s1 = Bias[r1];
    #pragma unroll
    for (int i = 0; i < 16; ++i) {
      int kk = (i + tid) & 15;
      s0 += Ps[kk * PSTR + o0];
      s1 += Ps[kk * PSTR + o1];
    }
    if (gsel == 1) {                 // g (tanh), o (sigmoid)
      float gg = tanhf(s0);
      float og = 1.f / (1.f + __expf(-s1));
      Ex[p2 * 2] = gg; Ex[p2 * 2 + 1] = og;
    }
    __syncthreads();
    if (gsel == 0) {                 // i, f + state update
      float ig = 1.f / (1.f + __expf(-s0));
      float fg = 1.f / (1.f + __expf(-s1));
      float gg = Ex[p2 * 2], og = Ex[p2 * 2 + 1];
      float c_old = Cs[p2];
      float h_old = hsrc[(size_t)(b0 + bbp) * H + khid + jj];  // exact fp32
      float c_new = fg * c_old + ig * gg;
      float h_new = og * tanhf(c_new);
      bool live = (t < Lens[bbp]);
      float h_next = live ? h_new : h_old;
      float c_next = live ? c_new : c_old;
      float rr = (float)resets[(b0 + bbp) * T + t];
      out[((size_t)(b0 + bbp) * T + t) * H + khid + jj] = h_next;
      carry_h = h_next * (1.f - rr);
      carry_c = c_next * (1.f - rr);
      Cs[p2] = carry_c;
      hdst[(size_t)(b0 + bbp) * H + khid + jj] = carry_h;
    }
    if (t < T - 1) { group_barrier(mybar, 64 * bar); bar++; }
  }
  if (gsel == 0) {
    out[OUT_HT + (size_t)(b0 + bbp) * H + khid + jj] = carry_h;
    out[OUT_CT + (size_t)(b0 + bbp) * H + khid + jj] = carry_c;
  }
}

__global__ void mask_kernel(const int* __restrict__ lengths, float* __restrict__ om) {
  int i = blockIdx.x * 256 + threadIdx.x;
  if (i < B * T) {
    int b = i >> 9, t = i & (T - 1);
    om[i] = (t < lengths[b]) ? 1.f : 0.f;
  }
}

extern "C" void kernel_launch(void* const* d_in, const int* in_sizes, int n_in,
                              void* d_out, int out_size, void* d_ws, size_t ws_size,
                              hipStream_t stream) {
  const int* inputs    = (const int*)d_in[0];
  const int* lengths   = (const int*)d_in[1];
  const int* resets    = (const int*)d_in[2];
  const float* emb     = (const float*)d_in[3];
  const float* W_ih    = (const float*)d_in[4];
  const float* W_hh    = (const float*)d_in[5];
  const float* b_ih    = (const float*)d_in[6];
  const float* b_hh    = (const float*)d_in[7];
  float* out = (float*)d_out;

  // ws layout: [0,4096): barrier counters; [4096, +256KB): h ping-pong buffer
  int* ctr = (int*)d_ws;
  float* hbuf = (float*)((char*)d_ws + 4096);

  // allow >64KB dynamic LDS (gfx950 has 160KB/CU)
  hipFuncSetAttribute((const void*)lstm_persistent,
                      hipFuncAttributeMaxDynamicSharedMemorySize, LDS_BYTES);

  hipMemsetAsync(d_ws, 0, 4096, stream);  // zero barrier counters every call
  mask_kernel<<<(B * T + 255) / 256, 256, 0, stream>>>(lengths, out + OUT_MASK);
  lstm_persistent<<<NG * BPG, NTHR, LDS_BYTES, stream>>>(
      inputs, lengths, resets, emb, W_ih, W_hh, b_ih, b_hh, out, ctr, hbuf);
}

// Round 2
// 6252.140 us; speedup vs baseline: 2.1745x; 2.1745x over previous
//
#include <hip/hip_runtime.h>
#include <stdint.h>
#include <stddef.h>

// Problem constants
constexpr int V = 32000, E = 256, H = 512, B = 64, T = 512;
constexpr int NTHR = 512;        // 8 waves
constexpr int BATG = 16;         // batches per group
constexpr int HPB = 8;           // hidden units per block (32 gate rows)

// LDS offsets (dynamic, 84KB requested to pin 1 block/CU)
constexpr int OFF_PS   = 0;                        // 8 waves * 640 floats
constexpr int OFF_G    = OFF_PS + 8 * 640 * 4;     // 20480: 512 activated gates
constexpr int OFF_BIAS = OFF_G + 512 * 4;          // 22528
constexpr int OFF_CS   = OFF_BIAS + 32 * 4;        // 22656
constexpr int OFF_LEN  = OFF_CS + 128 * 4;         // 23168
constexpr int OFF_TOK  = OFF_LEN + 16 * 4;         // 23232
constexpr int LDS_BYTES = 84 * 1024;               // force 1 block/CU

// Output layout (flat fp32): output | hT | cT | mask
constexpr size_t OUT_HT   = (size_t)B * T * H;
constexpr size_t OUT_CT   = OUT_HT + (size_t)B * H;
constexpr size_t OUT_MASK = OUT_CT + (size_t)B * H;

typedef __attribute__((ext_vector_type(8))) short short8;   // 8 bf16
typedef __attribute__((ext_vector_type(4))) float f32x4;

__device__ __forceinline__ unsigned short f2bf(float f) {   // RNE fp32->bf16
  uint32_t u = __builtin_bit_cast(uint32_t, f);
  return (unsigned short)((u + 0x7fffu + ((u >> 16) & 1u)) >> 16);
}
__device__ __forceinline__ short8 pack_bf8(float4 v0, float4 v1) {
  short8 r;
  r[0] = (short)f2bf(v0.x); r[1] = (short)f2bf(v0.y);
  r[2] = (short)f2bf(v0.z); r[3] = (short)f2bf(v0.w);
  r[4] = (short)f2bf(v1.x); r[5] = (short)f2bf(v1.y);
  r[6] = (short)f2bf(v1.z); r[7] = (short)f2bf(v1.w);
  return r;
}

// 64-block group barrier: release add, RELAXED spin (no per-poll L2 inv),
// single acquire fence on exit.
__device__ __forceinline__ void group_barrier(int* c, int target) {
  __syncthreads();
  if (threadIdx.x == 0) {
    __hip_atomic_fetch_add(c, 1, __ATOMIC_RELEASE, __HIP_MEMORY_SCOPE_AGENT);
    while (__hip_atomic_load(c, __ATOMIC_RELAXED, __HIP_MEMORY_SCOPE_AGENT) < target)
      __builtin_amdgcn_s_sleep(1);
    __builtin_amdgcn_fence(__ATOMIC_ACQUIRE, "agent");
  }
  __syncthreads();
}

__global__ void __launch_bounds__(NTHR, 1)
lstm_mfma(const int* __restrict__ inputs, const int* __restrict__ lengths,
          const int* __restrict__ resets, const float* __restrict__ emb,
          const float* __restrict__ W_ih, const float* __restrict__ W_hh,
          const float* __restrict__ b_ih, const float* __restrict__ b_hh,
          float* __restrict__ out, int* __restrict__ ctr,
          float* __restrict__ hbuf) {
  extern __shared__ char lds[];
  float* Ps = (float*)(lds + OFF_PS);     // [wave][n(32) * 20 + batch]
  float* G = (float*)(lds + OFF_G);       // activated gates [n*16 + b]
  float* Bias = (float*)(lds + OFF_BIAS);
  float* Cs = (float*)(lds + OFF_CS);     // c state [jj*16 + bb]
  int* Lens = (int*)(lds + OFF_LEN);
  int* Tok = (int*)(lds + OFF_TOK);

  const int tid = threadIdx.x;
  const int blk = blockIdx.x;
  const int grp = blk & 3;        // batch group (XCD pair {g, g+4})
  const int rq = blk >> 2;        // row chunk 0..63
  const int khid = rq * HPB;
  const int b0 = grp * BATG;
  int* mybar = ctr + grp * 64;

  const int w = tid >> 6;         // wave 0..7 : K-slice [96w, 96w+96)
  const int L = tid & 63;
  const int lc = L & 15;          // A: batch m | B/D: col n within tile
  const int q = L >> 4;           // quad

  // ---- persistent W fragments: wf[tile][s], tile n-range 16*tile..+15
  short8 wf[2][3];
  #pragma unroll
  for (int tl = 0; tl < 2; ++tl) {
    #pragma unroll
    for (int s = 0; s < 3; ++s) {
      const int kk = 96 * w + 32 * s + 8 * q;
      const int n = 16 * tl + lc;
      const int grow = (n >> 3) * H + khid + (n & 7);
      const float* src = (kk < 512) ? (W_hh + (size_t)grow * H + kk)
                                    : (W_ih + (size_t)grow * E + (kk - 512));
      float4 v0 = *(const float4*)src;
      float4 v1 = *(const float4*)(src + 4);
      wf[tl][s] = pack_bf8(v0, v1);
    }
  }
  if (tid < 32) {
    const int grow = (tid >> 3) * H + khid + (tid & 7);
    Bias[tid] = b_ih[grow] + b_hh[grow];
  }
  if (tid < 16) Lens[tid] = lengths[b0 + tid];
  if (tid < 128) Cs[tid] = 0.f;
  if (tid < 128) {                // zero h ping-pong buffer 0 (our slice)
    int bb = tid >> 3, j = tid & 7;
    hbuf[(size_t)(b0 + bb) * H + khid + j] = 0.f;
  }
  int bar = 1;
  group_barrier(mybar, 64 * bar); bar++;

  const int jj = tid >> 4;        // epilogue ids (tid<128): hidden j
  const int bb = tid & 15;        // batch

  float carry_h = 0.f, carry_c = 0.f;

  for (int t = 0; t < T; ++t) {
    const float* hsrc = hbuf + (size_t)(t & 1) * (B * H);
    float* hdst = hbuf + (size_t)((t + 1) & 1) * (B * H);

    if (tid < 16) Tok[tid] = inputs[(b0 + tid) * T + t];
    // prefetch epilogue operands (hidden under MFMA phase)
    float h_old = 0.f, rr = 0.f;
    if (tid < 128) {
      h_old = hsrc[(size_t)(b0 + bb) * H + khid + jj];
      rr = (float)resets[(b0 + bb) * T + t];
    }
    __syncthreads();

    // ---- A fragments direct from global + MFMA (K split across 8 waves)
    f32x4 acc0 = {0.f, 0.f, 0.f, 0.f};
    f32x4 acc1 = {0.f, 0.f, 0.f, 0.f};
    #pragma unroll
    for (int s = 0; s < 3; ++s) {
      const int kk = 96 * w + 32 * s + 8 * q;
      const float* src = (kk < 512)
          ? (hsrc + (size_t)(b0 + lc) * H + kk)
          : (emb + (size_t)Tok[lc] * E + (kk - 512));
      float4 v0 = *(const float4*)src;
      float4 v1 = *(const float4*)(src + 4);
      short8 a = pack_bf8(v0, v1);
      acc0 = __builtin_amdgcn_mfma_f32_16x16x32_bf16(a, wf[0][s], acc0, 0, 0, 0);
      acc1 = __builtin_amdgcn_mfma_f32_16x16x32_bf16(a, wf[1][s], acc1, 0, 0, 0);
    }
    // partials: D[m=4q+r][n=16*tl+lc] -> Ps[w*640 + n*20 + m]
    *(f32x4*)(Ps + w * 640 + lc * 20 + 4 * q) = acc0;
    *(f32x4*)(Ps + w * 640 + (16 + lc) * 20 + 4 * q) = acc1;
    __syncthreads();

    // ---- K-reduce across 8 waves + bias + activation (one gate per thread)
    {
      const int n = tid >> 4, b = tid & 15;
      float s = Bias[n];
      #pragma unroll
      for (int ww = 0; ww < 8; ++ww) s += Ps[ww * 640 + n * 20 + b];
      G[tid] = (n >= 16 && n < 24) ? tanhf(s) : 1.f / (1.f + __expf(-s));
    }
    __syncthreads();

    // ---- state update (128 threads: one (hidden, batch) pair each)
    if (tid < 128) {
      float ig = G[jj * 16 + bb];
      float fg = G[(8 + jj) * 16 + bb];
      float gg = G[(16 + jj) * 16 + bb];
      float og = G[(24 + jj) * 16 + bb];
      float c_old = Cs[tid];
      float c_new = fg * c_old + ig * gg;
      float h_new = og * tanhf(c_new);
      bool live = (t < Lens[bb]);
      float h_next = live ? h_new : h_old;
      float c_next = live ? c_new : c_old;
      out[((size_t)(b0 + bb) * T + t) * H + khid + jj] = h_next;
      carry_h = h_next * (1.f - rr);
      carry_c = c_next * (1.f - rr);
      Cs[tid] = carry_c;
      hdst[(size_t)(b0 + bb) * H + khid + jj] = carry_h;
    }
    if (t < T - 1) { group_barrier(mybar, 64 * bar); bar++; }
  }
  if (tid < 128) {
    out[OUT_HT + (size_t)(b0 + bb) * H + khid + jj] = carry_h;
    out[OUT_CT + (size_t)(b0 + bb) * H + khid + jj] = carry_c;
  }
}

__global__ void mask_kernel(const int* __restrict__ lengths, float* __restrict__ om) {
  int i = blockIdx.x * 256 + threadIdx.x;
  if (i < B * T) {
    int b = i >> 9, t = i & (T - 1);
    om[i] = (t < lengths[b]) ? 1.f : 0.f;
  }
}

extern "C" void kernel_launch(void* const* d_in, const int* in_sizes, int n_in,
                              void* d_out, int out_size, void* d_ws, size_t ws_size,
                              hipStream_t stream) {
  const int* inputs    = (const int*)d_in[0];
  const int* lengths   = (const int*)d_in[1];
  const int* resets    = (const int*)d_in[2];
  const float* emb     = (const float*)d_in[3];
  const float* W_ih    = (const float*)d_in[4];
  const float* W_hh    = (const float*)d_in[5];
  const float* b_ih    = (const float*)d_in[6];
  const float* b_hh    = (const float*)d_in[7];
  float* out = (float*)d_out;

  // ws layout: [0,4096): barrier counters; [4096, +256KB): h ping-pong buffer
  int* ctr = (int*)d_ws;
  float* hbuf = (float*)((char*)d_ws + 4096);

  hipFuncSetAttribute((const void*)lstm_mfma,
                      hipFuncAttributeMaxDynamicSharedMemorySize, LDS_BYTES);

  hipMemsetAsync(d_ws, 0, 4096, stream);  // zero barrier counters every call
  mask_kernel<<<(B * T + 255) / 256, 256, 0, stream>>>(lengths, out + OUT_MASK);
  lstm_mfma<<<256, NTHR, LDS_BYTES, stream>>>(
      inputs, lengths, resets, emb, W_ih, W_hh, b_ih, b_hh, out, ctr, hbuf);
}

// Round 3
// 3478.012 us; speedup vs baseline: 3.9090x; 1.7976x over previous
//
#include <hip/hip_runtime.h>
#include <stdint.h>
#include <stddef.h>

// Problem constants
constexpr int V = 32000, E = 256, H = 512, B = 64, T = 512;
constexpr int NTHR = 512;        // 8 waves
constexpr int BATG = 16;         // batches per group
constexpr int HPB = 8;           // hidden units per block (32 gate rows)

// LDS offsets (dynamic; request 84KB to pin 1 block/CU)
constexpr int OFF_PS   = 0;                        // 8 waves * 640 floats
constexpr int OFF_BIAS = OFF_PS + 8 * 640 * 4;     // 20480
constexpr int OFF_CS   = OFF_BIAS + 32 * 4;        // 20608
constexpr int OFF_LEN  = OFF_CS + 128 * 4;         // 21120
constexpr int LDS_BYTES = 84 * 1024;               // force 1 block/CU

// Output layout (flat fp32): output | hT | cT | mask
constexpr size_t OUT_HT   = (size_t)B * T * H;
constexpr size_t OUT_CT   = OUT_HT + (size_t)B * H;
constexpr size_t OUT_MASK = OUT_CT + (size_t)B * H;

typedef __attribute__((ext_vector_type(8))) short short8;   // 8 bf16
typedef __attribute__((ext_vector_type(4))) float f32x4;

__device__ __forceinline__ unsigned short f2bf(float f) {   // RNE fp32->bf16
  uint32_t u = __builtin_bit_cast(uint32_t, f);
  return (unsigned short)((u + 0x7fffu + ((u >> 16) & 1u)) >> 16);
}
__device__ __forceinline__ short8 pack_bf8(float4 v0, float4 v1) {
  short8 r;
  r[0] = (short)f2bf(v0.x); r[1] = (short)f2bf(v0.y);
  r[2] = (short)f2bf(v0.z); r[3] = (short)f2bf(v0.w);
  r[4] = (short)f2bf(v1.x); r[5] = (short)f2bf(v1.y);
  r[6] = (short)f2bf(v1.z); r[7] = (short)f2bf(v1.w);
  return r;
}
__device__ __forceinline__ float sigmoidf_fast(float x) {
  return 1.f / (1.f + __expf(-x));
}

// Agent-scope relaxed atomics: coherent at MALL, no L2 writeback/invalidate.
__device__ __forceinline__ void st_agent(float* p, float v) {
  __hip_atomic_store(p, v, __ATOMIC_RELAXED, __HIP_MEMORY_SCOPE_AGENT);
}
__device__ __forceinline__ float ld_agent(const float* p) {
  return __hip_atomic_load(p, __ATOMIC_RELAXED, __HIP_MEMORY_SCOPE_AGENT);
}

__global__ void __launch_bounds__(NTHR, 1)
lstm_mfma(const int* __restrict__ inputs, const int* __restrict__ lengths,
          const int* __restrict__ resets, const float* __restrict__ emb,
          const float* __restrict__ W_ih, const float* __restrict__ W_hh,
          const float* __restrict__ b_ih, const float* __restrict__ b_hh,
          float* __restrict__ out, int* __restrict__ ctr,
          float* __restrict__ hbuf) {
  extern __shared__ char lds[];
  float* Ps = (float*)(lds + OFF_PS);     // [wave][n(32)*20 + m(16)]
  float* Bias = (float*)(lds + OFF_BIAS);
  float* Cs = (float*)(lds + OFF_CS);     // c state [jj*16 + bb]
  int* Lens = (int*)(lds + OFF_LEN);

  const int tid = threadIdx.x;
  const int blk = blockIdx.x;
  const int grp = blk & 3;        // batch group
  const int rq = blk >> 2;        // row chunk 0..63
  const int khid = rq * HPB;
  const int b0 = grp * BATG;
  int* flags = ctr + grp * 64;    // one int per block in group

  const int w = tid >> 6;         // wave 0..7 : K-slice [96w, 96w+96)
  const int L = tid & 63;
  const int lc = L & 15;          // A: batch m | B/D: col n within tile
  const int q = L >> 4;           // quad

  // ---- persistent W fragments (bf16): wf[tile][s]
  short8 wf[2][3];
  #pragma unroll
  for (int tl = 0; tl < 2; ++tl) {
    #pragma unroll
    for (int s = 0; s < 3; ++s) {
      const int kk = 96 * w + 32 * s + 8 * q;
      const int n = 16 * tl + lc;
      const int grow = (n >> 3) * H + khid + (n & 7);
      const float* src = (kk < 512) ? (W_hh + (size_t)grow * H + kk)
                                    : (W_ih + (size_t)grow * E + (kk - 512));
      float4 v0 = *(const float4*)src;
      float4 v1 = *(const float4*)(src + 4);
      wf[tl][s] = pack_bf8(v0, v1);
    }
  }
  if (tid < 32) {
    const int grow = (tid >> 3) * H + khid + (tid & 7);
    Bias[tid] = b_ih[grow] + b_hh[grow];
  }
  if (tid < 16) Lens[tid] = lengths[b0 + tid];
  if (tid < 128) Cs[tid] = 0.f;
  const int jj = tid >> 4;        // epilogue ids (tid<128 only): hidden j 0..7
  const int bb = tid & 15;        // batch 0..15
  if (tid < 128) {                // h_0 = 0 (own slice), MALL-visible
    st_agent(&hbuf[(size_t)(b0 + bb) * H + khid + jj], 0.f);
  }
  __syncthreads();                // drains vmcnt -> h0 stores MALL-acked
  if (tid == 0) {
    __hip_atomic_store(&flags[rq], 1, __ATOMIC_RELAXED, __HIP_MEMORY_SCOPE_AGENT);
  }

  float carry_h = 0.f, carry_c = 0.f;

  for (int t = 0; t < T; ++t) {
    const float* hsrc = hbuf + (size_t)(t & 1) * (B * H);
    float* hdst = hbuf + (size_t)((t + 1) & 1) * (B * H);

    // ---- pre-barrier work (independent of other blocks' h_t)
    float h_old = 0.f, rr = 0.f;
    if (tid < 128) {              // own slice: written by self last step
      h_old = ld_agent(&hsrc[(size_t)(b0 + bb) * H + khid + jj]);
      rr = (float)resets[(b0 + bb) * T + t];
    }
    short8 afrag[3];
    #pragma unroll
    for (int s = 0; s < 3; ++s) { // emb side of A (waves 5..7): t-dep only
      const int kk = 96 * w + 32 * s + 8 * q;
      if (kk >= 512) {
        const int tok = inputs[(b0 + lc) * T + t];
        const float* src = emb + (size_t)tok * E + (kk - 512);
        afrag[s] = pack_bf8(*(const float4*)src, *(const float4*)(src + 4));
      }
    }

    // ---- flag barrier: wave 0 polls all 64 group flags (one per lane)
    if (w == 0) {
      const int target = t + 1;
      while (true) {
        int v = __hip_atomic_load(&flags[L], __ATOMIC_RELAXED,
                                  __HIP_MEMORY_SCOPE_AGENT);
        if (__all(v >= target)) break;
        __builtin_amdgcn_s_sleep(0);
      }
    }
    __syncthreads();

    // ---- h side of A (MALL-coherent loads) + MFMA
    f32x4 acc0 = {0.f, 0.f, 0.f, 0.f};
    f32x4 acc1 = {0.f, 0.f, 0.f, 0.f};
    #pragma unroll
    for (int s = 0; s < 3; ++s) {
      const int kk = 96 * w + 32 * s + 8 * q;
      if (kk < 512) {
        const float* src = hsrc + (size_t)(b0 + lc) * H + kk;
        short8 a;
        #pragma unroll
        for (int j = 0; j < 8; ++j) a[j] = (short)f2bf(ld_agent(src + j));
        afrag[s] = a;
      }
      acc0 = __builtin_amdgcn_mfma_f32_16x16x32_bf16(afrag[s], wf[0][s], acc0, 0, 0, 0);
      acc1 = __builtin_amdgcn_mfma_f32_16x16x32_bf16(afrag[s], wf[1][s], acc1, 0, 0, 0);
    }
    // partials: D[m=4q+r][n] -> Ps[w*640 + n*20 + m]
    *(f32x4*)(Ps + w * 640 + lc * 20 + 4 * q) = acc0;
    *(f32x4*)(Ps + w * 640 + (16 + lc) * 20 + 4 * q) = acc1;
    __syncthreads();

    // ---- fused reduce + activations + state update (128 threads)
    if (tid < 128) {
      float g4[4];
      #pragma unroll
      for (int gi = 0; gi < 4; ++gi) {
        const int n = gi * 8 + jj;
        float s = Bias[n];
        #pragma unroll
        for (int ww = 0; ww < 8; ++ww) s += Ps[ww * 640 + n * 20 + bb];
        g4[gi] = s;
      }
      float ig = sigmoidf_fast(g4[0]);
      float fg = sigmoidf_fast(g4[1]);
      float gg = tanhf(g4[2]);
      float og = sigmoidf_fast(g4[3]);
      float c_old = Cs[tid];
      float c_new = fg * c_old + ig * gg;
      float h_new = og * tanhf(c_new);
      bool live = (t < Lens[bb]);
      float h_next = live ? h_new : h_old;
      float c_next = live ? c_new : c_old;
      out[((size_t)(b0 + bb) * T + t) * H + khid + jj] = h_next;
      carry_h = h_next * (1.f - rr);
      carry_c = c_next * (1.f - rr);
      Cs[tid] = carry_c;
      st_agent(&hdst[(size_t)(b0 + bb) * H + khid + jj], carry_h);
    }
    if (t < T - 1) {
      __syncthreads();            // per-thread vmcnt(0): h stores MALL-acked
      if (tid == 0) {
        __hip_atomic_store(&flags[rq], t + 2, __ATOMIC_RELAXED,
                           __HIP_MEMORY_SCOPE_AGENT);
      }
    }
  }
  if (tid < 128) {
    out[OUT_HT + (size_t)(b0 + bb) * H + khid + jj] = carry_h;
    out[OUT_CT + (size_t)(b0 + bb) * H + khid + jj] = carry_c;
  }
}

__global__ void mask_kernel(const int* __restrict__ lengths, float* __restrict__ om) {
  int i = blockIdx.x * 256 + threadIdx.x;
  if (i < B * T) {
    int b = i >> 9, t = i & (T - 1);
    om[i] = (t < lengths[b]) ? 1.f : 0.f;
  }
}

extern "C" void kernel_launch(void* const* d_in, const int* in_sizes, int n_in,
                              void* d_out, int out_size, void* d_ws, size_t ws_size,
                              hipStream_t stream) {
  const int* inputs    = (const int*)d_in[0];
  const int* lengths   = (const int*)d_in[1];
  const int* resets    = (const int*)d_in[2];
  const float* emb     = (const float*)d_in[3];
  const float* W_ih    = (const float*)d_in[4];
  const float* W_hh    = (const float*)d_in[5];
  const float* b_ih    = (const float*)d_in[6];
  const float* b_hh    = (const float*)d_in[7];
  float* out = (float*)d_out;

  // ws layout: [0,4096): flags; [4096, +256KB): h ping-pong buffer
  int* ctr = (int*)d_ws;
  float* hbuf = (float*)((char*)d_ws + 4096);

  hipFuncSetAttribute((const void*)lstm_mfma,
                      hipFuncAttributeMaxDynamicSharedMemorySize, LDS_BYTES);

  hipMemsetAsync(d_ws, 0, 4096, stream);  // flags = 0 (blocks post 1 after init)
  mask_kernel<<<(B * T + 255) / 256, 256, 0, stream>>>(lengths, out + OUT_MASK);
  lstm_mfma<<<256, NTHR, LDS_BYTES, stream>>>(
      inputs, lengths, resets, emb, W_ih, W_hh, b_ih, b_hh, out, ctr, hbuf);
}